// Round 6
// baseline (423.567 us; speedup 1.0000x reference)
//
#include <hip/hip_runtime.h>
#include <hip/hip_bf16.h>

typedef __attribute__((ext_vector_type(8))) short short8;
typedef __attribute__((ext_vector_type(4))) float f32x4;

#define V_ 50000
#define E_ 300000
#define B_ 4
#define LAT_ 512
#define H_ 128
#define L_ 3
#define N_ (B_*V_)

#define SCAN_B 512
#define SCAN_G ((V_ + SCAN_B - 1) / SCAN_B)   // 98

__device__ inline void bsplit(float v, ushort& hi, ushort& lo) {
    __hip_bfloat16 hb = __float2bfloat16(v);
    float hf = __bfloat162float(hb);
    __hip_bfloat16 lb = __float2bfloat16(v - hf);
    hi = *(ushort*)&hb; lo = *(ushort*)&lb;
}
__device__ inline float bjoin(ushort h, ushort l) {
    __hip_bfloat16 hb = *(__hip_bfloat16*)&h;
    __hip_bfloat16 lb = *(__hip_bfloat16*)&l;
    return __bfloat162float(hb) + __bfloat162float(lb);
}
// Row swizzle, bits 5-7: per-read-instruction the column byte's bits 5-7 are
// wave-uniform (hi-half flag + ks), so XOR-ing row&7 there is a pure lane
// permutation -> bank-conflict-free b64 reads.  16B-granularity preserved.
__device__ inline int swzr(int row) { return (row & 7) << 5; }

// ---------------------------------------------------------------------------
// Graph preprocessing
// ---------------------------------------------------------------------------

__global__ void k_zero(int* __restrict__ deg, int* __restrict__ cursor) {
    int i = blockIdx.x * 256 + threadIdx.x;
    if (i < V_) { deg[i] = 0; cursor[i] = 0; }
}

__global__ void k_deg(const int* __restrict__ dst, int* __restrict__ deg) {
    int e = blockIdx.x * 256 + threadIdx.x;
    if (e < E_) atomicAdd(&deg[dst[e]], 1);
}

__global__ __launch_bounds__(SCAN_B) void k_scan1(const int* __restrict__ deg,
                                                  int* __restrict__ off,
                                                  float* __restrict__ dis,
                                                  int* __restrict__ part) {
    int t = threadIdx.x;
    int i = blockIdx.x * SCAN_B + t;
    int d = (i < V_) ? deg[i] : 0;
    __shared__ int sm[SCAN_B];
    sm[t] = d;
    __syncthreads();
    int val = d;
    for (int s = 1; s < SCAN_B; s <<= 1) {
        int o = (t >= s) ? sm[t - s] : 0;
        __syncthreads();
        val += o;
        sm[t] = val;
        __syncthreads();
    }
    if (i < V_) {
        off[i] = val - d;
        dis[i] = rsqrtf((float)(B_ * d + 1));
    }
    if (t == SCAN_B - 1) part[blockIdx.x] = val;
}

__global__ void k_scan2(int* __restrict__ part) {
    __shared__ int sm[128];
    int t = threadIdx.x;
    int v = (t < SCAN_G) ? part[t] : 0;
    sm[t] = v;
    __syncthreads();
    int val = v;
    for (int s = 1; s < 128; s <<= 1) {
        int o = (t >= s) ? sm[t - s] : 0;
        __syncthreads();
        val += o;
        sm[t] = val;
        __syncthreads();
    }
    if (t < SCAN_G) part[t] = val - v;
}

__global__ __launch_bounds__(SCAN_B) void k_scan3(int* __restrict__ off,
                                                  const int* __restrict__ part) {
    int i = blockIdx.x * SCAN_B + threadIdx.x;
    if (i < V_) off[i] += part[blockIdx.x];
    if (i == 0) off[V_] = E_;
}

__global__ void k_fill(const int* __restrict__ src, const int* __restrict__ dst,
                       const int* __restrict__ off, int* __restrict__ cursor,
                       int* __restrict__ csr) {
    int e = blockIdx.x * 256 + threadIdx.x;
    if (e < E_) {
        int c = dst[e];
        int p = atomicAdd(&cursor[c], 1);
        csr[off[c] + p] = src[e];
    }
}

// ---------------------------------------------------------------------------
// Weight split + small prep
// ---------------------------------------------------------------------------

__global__ void k_wsplit(const float* __restrict__ W, ushort* __restrict__ Whi,
                         ushort* __restrict__ Wlo) {
    int i = blockIdx.x * 256 + threadIdx.x;
    float w = W[i];
    ushort hi, lo; bsplit(w, hi, lo);
    Whi[i] = hi; Wlo[i] = lo;
}

__global__ void k_prep(const float* __restrict__ Win, float* __restrict__ Wxyz) {
    int j = threadIdx.x;   // 128
    f32x4 v = {Win[(size_t)j*(LAT_+3)+0], Win[(size_t)j*(LAT_+3)+1],
               Win[(size_t)j*(LAT_+3)+2], 0.f};
    *(f32x4*)(Wxyz + j*4) = v;
}

__global__ void k_latproj(const float* __restrict__ Win, const float* __restrict__ bin,
                          const float* __restrict__ latent, float* __restrict__ latproj) {
    int t = blockIdx.x * 128 + threadIdx.x;
    if (t >= B_ * H_) return;
    int b = t >> 7, j = t & 127;
    const float* wr = Win + (size_t)j * (LAT_ + 3) + 3;
    const float* lp = latent + (size_t)b * LAT_;
    float s = bin[j];
    for (int k = 0; k < LAT_; k++) s = fmaf(wr[k], lp[k], s);
    latproj[t] = s;
}

// ---------------------------------------------------------------------------
// k_big: rows >= V (batches 1..3, no edges) fully fused:
// x0 -> 3 MFMA layers -> output head.  512 thr = 8 waves; 64-row tile;
// wave owns one 16-col slab.  ks-OUTER loop: only one ks-step of W live
// (8 VGPRs) -> no rematerialized loads.  LDS bits5-7 row swizzle ->
// conflict-free b64 A-frag reads.
// ---------------------------------------------------------------------------

__global__ __launch_bounds__(512, 4) void k_big(
        const float* __restrict__ xyz, const float* __restrict__ latproj,
        const float* __restrict__ Wxyz,
        const ushort* __restrict__ Whi, const ushort* __restrict__ Wlo,
        const float* __restrict__ convb,
        const float* __restrict__ Wout, const float* __restrict__ bout,
        float* __restrict__ out) {
    __shared__ __align__(16) char smem[32768];
    const int tid = threadIdx.x;
    const int row0 = V_ + blockIdx.x * 64;
    const int lane = tid & 63;
    const int wid  = tid >> 6;
    const int l15  = lane & 15;
    const int kg   = lane >> 4;
    const int n0   = wid * 16;
    const int tr   = tid >> 4;          // 0..31
    const int c0   = (tid & 15) * 8;    // elem base, 8 elems = 16 B

    // ---- x0 ----
#pragma unroll
    for (int rep = 0; rep < 2; rep++) {
        int row = tr + rep * 32;
        int node = row0 + row;
        ushort hs[8], ls[8];
        if (node < N_) {
            int v = node % V_, b = node / V_;
            float xv0 = xyz[v*3+0], xv1 = xyz[v*3+1], xv2 = xyz[v*3+2];
#pragma unroll
            for (int i = 0; i < 8; i++) {
                int j = c0 + i;
                f32x4 wx = *(const f32x4*)(Wxyz + j*4);
                float s = latproj[b*H_ + j];
                s = fmaf(wx[0], xv0, s);
                s = fmaf(wx[1], xv1, s);
                s = fmaf(wx[2], xv2, s);
                s = fmaxf(s, 0.f);
                bsplit(s, hs[i], ls[i]);
            }
        } else {
#pragma unroll
            for (int i = 0; i < 8; i++) { hs[i] = 0; ls[i] = 0; }
        }
        int bo = (c0*2) ^ swzr(row);
        *(uint4*)(smem + row*256 + bo) = *(uint4*)hs;
        *(uint4*)(smem + 16384 + row*256 + bo) = *(uint4*)ls;
    }
    __syncthreads();

    for (int l = 0; l < L_; l++) {
        const ushort* Whp = Whi + (size_t)l*H_*H_ + (size_t)(n0 + l15)*H_ + kg*4;
        const ushort* Wlp = Wlo + (size_t)l*H_*H_ + (size_t)(n0 + l15)*H_ + kg*4;
        f32x4 acc[4];
#pragma unroll
        for (int mt = 0; mt < 4; mt++) acc[mt] = (f32x4){0.f,0.f,0.f,0.f};
#pragma unroll
        for (int ks = 0; ks < 4; ks++) {
            union { short8 v; uint2 u[2]; } wh, wl;
            wh.u[0] = *(const uint2*)(Whp + ks*32);
            wh.u[1] = *(const uint2*)(Whp + ks*32 + 16);
            wl.u[0] = *(const uint2*)(Wlp + ks*32);
            wl.u[1] = *(const uint2*)(Wlp + ks*32 + 16);
            int cc = ks*64 + kg*8;
#pragma unroll
            for (int mt = 0; mt < 4; mt++) {
                int row = mt*16 + l15;
                int sw = swzr(row);
                const char* rbh = smem + row*256;
                const char* rbl = rbh + 16384;
                union { short8 v; uint2 u[2]; } ah, al;
                ah.u[0] = *(const uint2*)(rbh + (cc ^ sw));
                ah.u[1] = *(const uint2*)(rbh + ((cc+32) ^ sw));
                al.u[0] = *(const uint2*)(rbl + (cc ^ sw));
                al.u[1] = *(const uint2*)(rbl + ((cc+32) ^ sw));
                acc[mt] = __builtin_amdgcn_mfma_f32_16x16x32_bf16(ah.v, wh.v, acc[mt], 0,0,0);
                acc[mt] = __builtin_amdgcn_mfma_f32_16x16x32_bf16(al.v, wh.v, acc[mt], 0,0,0);
                acc[mt] = __builtin_amdgcn_mfma_f32_16x16x32_bf16(ah.v, wl.v, acc[mt], 0,0,0);
            }
        }
        __syncthreads();          // all waves done READING x
        float bv = convb[l*H_ + n0 + l15];
        int bo = (n0 + l15) * 2;
#pragma unroll
        for (int mt = 0; mt < 4; mt++)
#pragma unroll
            for (int j = 0; j < 4; j++) {
                int row = mt*16 + kg*4 + j;
                int sw = swzr(row);
                float v = fmaxf(acc[mt][j] + bv, 0.f);
                ushort hi, lo; bsplit(v, hi, lo);
                *(ushort*)(smem + row*256 + (bo ^ sw)) = hi;
                *(ushort*)(smem + 16384 + row*256 + (bo ^ sw)) = lo;
            }
        __syncthreads();          // x' fully written
    }

    // ---- output head ----
    float wo0[8], wo1[8], wo2[8];
#pragma unroll
    for (int i = 0; i < 8; i++) {
        wo0[i] = Wout[0*H_ + c0 + i];
        wo1[i] = Wout[1*H_ + c0 + i];
        wo2[i] = Wout[2*H_ + c0 + i];
    }
#pragma unroll
    for (int rep = 0; rep < 2; rep++) {
        int row = tr + rep*32;
        int node = row0 + row;
        int bo = (c0*2) ^ swzr(row);
        uint4 uh = *(const uint4*)(smem + row*256 + bo);
        uint4 ul = *(const uint4*)(smem + 16384 + row*256 + bo);
        const ushort* hp = (const ushort*)&uh;
        const ushort* lp = (const ushort*)&ul;
        float p0 = 0.f, p1 = 0.f, p2 = 0.f;
#pragma unroll
        for (int i = 0; i < 8; i++) {
            float xv = bjoin(hp[i], lp[i]);
            p0 = fmaf(xv, wo0[i], p0);
            p1 = fmaf(xv, wo1[i], p1);
            p2 = fmaf(xv, wo2[i], p2);
        }
#pragma unroll
        for (int m = 1; m < 16; m <<= 1) {
            p0 += __shfl_xor(p0, m);
            p1 += __shfl_xor(p1, m);
            p2 += __shfl_xor(p2, m);
        }
        if ((tid & 15) == 0 && node < N_) {
            out[(size_t)node*3 + 0] = p0 + bout[0];
            out[(size_t)node*3 + 1] = p1 + bout[1];
            out[(size_t)node*3 + 2] = p2 + bout[2];
        }
    }
}

// ---------------------------------------------------------------------------
// k_lay0: batch-0 GEMM h = x @ W^T, rows < V.  Same structure as one k_big
// layer (ks-outer, swizzled LDS).  MODE 0: x0 in-kernel; MODE 1: stage
// xh/xl from global.  Epilogue: f32 h to global.
// ---------------------------------------------------------------------------

template<int MODE>
__global__ __launch_bounds__(512, 4) void k_lay0(
        const ushort* __restrict__ xh, const ushort* __restrict__ xl,
        const float* __restrict__ xyz, const float* __restrict__ latproj,
        const float* __restrict__ Wxyz,
        const ushort* __restrict__ Whp0, const ushort* __restrict__ Wlp0,
        float* __restrict__ h) {
    __shared__ __align__(16) char smem[32768];
    const int tid = threadIdx.x;
    const int row0 = blockIdx.x * 64;
    const int lane = tid & 63;
    const int wid  = tid >> 6;
    const int l15  = lane & 15;
    const int kg   = lane >> 4;
    const int n0   = wid * 16;
    const int tr   = tid >> 4;
    const int c0   = (tid & 15) * 8;

    if (MODE == 0) {
#pragma unroll
        for (int rep = 0; rep < 2; rep++) {
            int row = tr + rep * 32;
            int v = row0 + row;
            ushort hs[8], ls[8];
            if (v < V_) {
                float xv0 = xyz[v*3+0], xv1 = xyz[v*3+1], xv2 = xyz[v*3+2];
#pragma unroll
                for (int i = 0; i < 8; i++) {
                    int j = c0 + i;
                    f32x4 wx = *(const f32x4*)(Wxyz + j*4);
                    float s = latproj[j];                       // b = 0
                    s = fmaf(wx[0], xv0, s);
                    s = fmaf(wx[1], xv1, s);
                    s = fmaf(wx[2], xv2, s);
                    s = fmaxf(s, 0.f);
                    bsplit(s, hs[i], ls[i]);
                }
            } else {
#pragma unroll
                for (int i = 0; i < 8; i++) { hs[i] = 0; ls[i] = 0; }
            }
            int bo = (c0*2) ^ swzr(row);
            *(uint4*)(smem + row*256 + bo) = *(uint4*)hs;
            *(uint4*)(smem + 16384 + row*256 + bo) = *(uint4*)ls;
        }
    } else {
#pragma unroll
        for (int k = 0; k < 4; k++) {
            int chunk = tid + k*512;            // 2048 x 16B
            int p  = chunk >> 10;
            int r  = (chunk >> 4) & 63;
            int cb = (chunk & 15) * 16;
            int grow = row0 + r;
            uint4 g = {0u,0u,0u,0u};
            if (grow < V_)
                g = *(const uint4*)((const char*)((p ? xl : xh) + (size_t)grow*H_) + cb);
            *(uint4*)(smem + p*16384 + r*256 + (cb ^ swzr(r))) = g;
        }
    }
    __syncthreads();

    const ushort* Whp = Whp0 + (size_t)(n0 + l15)*H_ + kg*4;
    const ushort* Wlp = Wlp0 + (size_t)(n0 + l15)*H_ + kg*4;
    f32x4 acc[4];
#pragma unroll
    for (int mt = 0; mt < 4; mt++) acc[mt] = (f32x4){0.f,0.f,0.f,0.f};
#pragma unroll
    for (int ks = 0; ks < 4; ks++) {
        union { short8 v; uint2 u[2]; } wh, wl;
        wh.u[0] = *(const uint2*)(Whp + ks*32);
        wh.u[1] = *(const uint2*)(Whp + ks*32 + 16);
        wl.u[0] = *(const uint2*)(Wlp + ks*32);
        wl.u[1] = *(const uint2*)(Wlp + ks*32 + 16);
        int cc = ks*64 + kg*8;
#pragma unroll
        for (int mt = 0; mt < 4; mt++) {
            int row = mt*16 + l15;
            int sw = swzr(row);
            const char* rbh = smem + row*256;
            const char* rbl = rbh + 16384;
            union { short8 v; uint2 u[2]; } ah, al;
            ah.u[0] = *(const uint2*)(rbh + (cc ^ sw));
            ah.u[1] = *(const uint2*)(rbh + ((cc+32) ^ sw));
            al.u[0] = *(const uint2*)(rbl + (cc ^ sw));
            al.u[1] = *(const uint2*)(rbl + ((cc+32) ^ sw));
            acc[mt] = __builtin_amdgcn_mfma_f32_16x16x32_bf16(ah.v, wh.v, acc[mt], 0,0,0);
            acc[mt] = __builtin_amdgcn_mfma_f32_16x16x32_bf16(al.v, wh.v, acc[mt], 0,0,0);
            acc[mt] = __builtin_amdgcn_mfma_f32_16x16x32_bf16(ah.v, wl.v, acc[mt], 0,0,0);
        }
    }

#pragma unroll
    for (int mt = 0; mt < 4; mt++)
#pragma unroll
        for (int j = 0; j < 4; j++) {
            int grow = row0 + mt*16 + kg*4 + j;
            if (grow < V_) h[(size_t)grow*H_ + n0 + l15] = acc[mt][j];
        }
}

// ---------------------------------------------------------------------------
// Aggregation (batch-0).  One wave per node; lane-parallel CSR prefetch.
// ---------------------------------------------------------------------------

template<bool FINAL>
__global__ __launch_bounds__(256) void k_agg0(const float* __restrict__ h,
                                              const float* __restrict__ dis,
                                              const int* __restrict__ off,
                                              const int* __restrict__ csr,
                                              const float* __restrict__ bias,
                                              ushort* __restrict__ xh_out,
                                              ushort* __restrict__ xl_out,
                                              const float* __restrict__ Wout,
                                              const float* __restrict__ bout,
                                              float* __restrict__ out) {
    int c = blockIdx.x * 4 + (threadIdx.x >> 6);
    int lane = threadIdx.x & 63;
    if (c >= V_) return;
    int beg = off[c], end = off[c + 1];
    int nu = end - beg;
    int   myu  = (lane < nu) ? csr[beg + lane] : 0;
    float mywu = (lane < nu) ? dis[myu] : 0.f;
    float a0 = 0.f, a1 = 0.f;
    int nn = nu < 64 ? nu : 64;
    for (int i = 0; i < nn; i++) {
        int u = __shfl(myu, i);
        float wu = __shfl(mywu, i);
        const float* hu = h + (size_t)u * 128;
        a0 = fmaf(wu, hu[lane],      a0);
        a1 = fmaf(wu, hu[lane + 64], a1);
    }
    for (int i = beg + 64; i < end; i++) {
        int u = csr[i];
        float wu = dis[u];
        const float* hu = h + (size_t)u * 128;
        a0 = fmaf(wu, hu[lane],      a0);
        a1 = fmaf(wu, hu[lane + 64], a1);
    }
    float dc = dis[c];
    const float* hr = h + (size_t)c * 128;
    float s0 = fmaxf(dc * (float)B_ * a0 + dc * dc * hr[lane]      + bias[lane],      0.f);
    float s1 = fmaxf(dc * (float)B_ * a1 + dc * dc * hr[lane + 64] + bias[lane + 64], 0.f);
    if (FINAL) {
        float p0 = s0 * Wout[0*H_ + lane] + s1 * Wout[0*H_ + 64 + lane];
        float p1 = s0 * Wout[1*H_ + lane] + s1 * Wout[1*H_ + 64 + lane];
        float p2 = s0 * Wout[2*H_ + lane] + s1 * Wout[2*H_ + 64 + lane];
#pragma unroll
        for (int d = 32; d; d >>= 1) {
            p0 += __shfl_down(p0, d);
            p1 += __shfl_down(p1, d);
            p2 += __shfl_down(p2, d);
        }
        if (lane == 0) {
            out[(size_t)c*3 + 0] = p0 + bout[0];
            out[(size_t)c*3 + 1] = p1 + bout[1];
            out[(size_t)c*3 + 2] = p2 + bout[2];
        }
    } else {
        ushort h0, l0, h1, l1;
        bsplit(s0, h0, l0);
        bsplit(s1, h1, l1);
        xh_out[(size_t)c*128 + lane]      = h0;
        xl_out[(size_t)c*128 + lane]      = l0;
        xh_out[(size_t)c*128 + lane + 64] = h1;
        xl_out[(size_t)c*128 + lane + 64] = l1;
    }
}

// ---------------------------------------------------------------------------

extern "C" void kernel_launch(void* const* d_in, const int* in_sizes, int n_in,
                              void* d_out, int out_size, void* d_ws, size_t ws_size,
                              hipStream_t stream) {
    const float* xyz    = (const float*)d_in[0];
    const float* latent = (const float*)d_in[1];
    const int*   ei     = (const int*)d_in[2];
    const float* Win    = (const float*)d_in[3];
    const float* bin    = (const float*)d_in[4];
    const float* convW  = (const float*)d_in[5];
    const float* convb  = (const float*)d_in[6];
    const float* Wout   = (const float*)d_in[7];
    const float* bout   = (const float*)d_in[8];
    float* out = (float*)d_out;

    char* w = (char*)d_ws;
    auto carve = [&](size_t bytes) {
        char* p = w;
        w += (bytes + 255) & ~(size_t)255;
        return p;
    };
    ushort* xh      = (ushort*)carve((size_t)V_ * H_ * 2);
    ushort* xl      = (ushort*)carve((size_t)V_ * H_ * 2);
    float*  h       = (float*)carve((size_t)V_ * H_ * 4);
    ushort* Whi     = (ushort*)carve((size_t)L_ * H_ * H_ * 2);
    ushort* Wlo     = (ushort*)carve((size_t)L_ * H_ * H_ * 2);
    float*  dis     = (float*)carve((size_t)V_ * 4);
    float*  latproj = (float*)carve((size_t)B_ * H_ * 4);
    float*  Wxyz    = (float*)carve((size_t)H_ * 4 * 4);
    int*    deg     = (int*)carve((size_t)V_ * 4);
    int*    off     = (int*)carve((size_t)(V_ + 1) * 4);
    int*    cursor  = (int*)carve((size_t)V_ * 4);
    int*    csr     = (int*)carve((size_t)E_ * 4);
    int*    part    = (int*)carve((size_t)SCAN_G * 4);
    (void)ws_size; (void)in_sizes; (void)n_in; (void)out_size;

    const int* src = ei;
    const int* dst = ei + E_;

    k_zero<<<(V_ + 255) / 256, 256, 0, stream>>>(deg, cursor);
    k_deg<<<(E_ + 255) / 256, 256, 0, stream>>>(dst, deg);
    k_scan1<<<SCAN_G, SCAN_B, 0, stream>>>(deg, off, dis, part);
    k_scan2<<<1, 128, 0, stream>>>(part);
    k_scan3<<<SCAN_G, SCAN_B, 0, stream>>>(off, part);
    k_fill<<<(E_ + 255) / 256, 256, 0, stream>>>(src, dst, off, cursor, csr);

    k_wsplit<<<(L_ * H_ * H_) / 256, 256, 0, stream>>>(convW, Whi, Wlo);
    k_prep<<<1, 128, 0, stream>>>(Win, Wxyz);
    k_latproj<<<4, 128, 0, stream>>>(Win, bin, latent, latproj);

    // batches 1..3: fully fused (no graph)
    k_big<<<(N_ - V_ + 63) / 64, 512, 0, stream>>>(xyz, latproj, Wxyz, Whi, Wlo,
                                                   convb, Wout, bout, out);

    // batch 0 chain
    const int GB0 = (V_ + 63) / 64;
    k_lay0<0><<<GB0, 512, 0, stream>>>(nullptr, nullptr, xyz, latproj, Wxyz,
                                       Whi, Wlo, h);
    k_agg0<false><<<(V_ + 3) / 4, 256, 0, stream>>>(h, dis, off, csr, convb,
                                                    xh, xl, nullptr, nullptr, nullptr);
    k_lay0<1><<<GB0, 512, 0, stream>>>(xh, xl, nullptr, nullptr, nullptr,
                                       Whi + (size_t)1*H_*H_, Wlo + (size_t)1*H_*H_, h);
    k_agg0<false><<<(V_ + 3) / 4, 256, 0, stream>>>(h, dis, off, csr, convb + 1*H_,
                                                    xh, xl, nullptr, nullptr, nullptr);
    k_lay0<1><<<GB0, 512, 0, stream>>>(xh, xl, nullptr, nullptr, nullptr,
                                       Whi + (size_t)2*H_*H_, Wlo + (size_t)2*H_*H_, h);
    k_agg0<true><<<(V_ + 3) / 4, 256, 0, stream>>>(h, dis, off, csr, convb + 2*H_,
                                                   nullptr, nullptr, Wout, bout, out);
}